// Round 7
// baseline (1494.957 us; speedup 1.0000x reference)
//
#include <hip/hip_runtime.h>

#define Bz 8
#define T1z 13
#define Tz 12
#define Vz 20000
#define Ez 512
#define Dz 512
#define Kz 512
#define Cz 2048
#define Pz 64
#define NB 256
#define NT 1024

typedef float floatx4 __attribute__((ext_vector_type(4)));

// ---- persistent-kernel grid barrier state (monotone generation counter) ----
__device__ unsigned g_slots[NB];
__device__ unsigned g_gen2;

__device__ __forceinline__ float waveReduce(float v) {
    #pragma unroll
    for (int off = 32; off > 0; off >>= 1) v += __shfl_xor(v, off);
    return v;
}

__device__ __forceinline__ float sigf(float x) { return 1.0f / (1.0f + expf(-x)); }

// Coherent (L1/L2-bypassing, NON-invalidating) scalar load.
__device__ __forceinline__ float ldcv(const float* p) {
    return __hip_atomic_load(p, __ATOMIC_RELAXED, __HIP_MEMORY_SCOPE_AGENT);
}

// Vector (dwordx4) coherent bypass loads; batched variants issue N loads
// before ONE waitcnt -> single L3 latency.
__device__ __forceinline__ float4 ldcv4a(const float4* p) {
    float4 r;
    asm volatile("global_load_dwordx4 %0, %1, off sc0 sc1\n\ts_waitcnt vmcnt(0)"
                 : "=&v"(r) : "v"(p) : "memory");
    return r;
}
__device__ __forceinline__ void ldcv4x2(float4& a, float4& b,
                                        const float4* pa, const float4* pb) {
    asm volatile("global_load_dwordx4 %0, %2, off sc0 sc1\n\t"
                 "global_load_dwordx4 %1, %3, off sc0 sc1\n\t"
                 "s_waitcnt vmcnt(0)"
                 : "=&v"(a), "=&v"(b) : "v"(pa), "v"(pb) : "memory");
}
// Coherent write-through store (value must be ext_vector_type, not float4 struct:
// clang can't pass struct INPUTS in a 'v' constraint; struct outputs are fine).
__device__ __forceinline__ void stcv4(float4* p, float4 v) {
    floatx4 w;
    w.x = v.x; w.y = v.y; w.z = v.z; w.w = v.w;
    asm volatile("global_store_dwordx4 %0, %1, off sc0 sc1" :: "v"(p), "v"(w) : "memory");
}

// Grid-wide barrier: RELAXED polls; ONE release store at arrival. No invalidate:
// cross-phase intermediates are read via bypass loads, L2 read-caches survive.
__device__ __forceinline__ void gridSync(unsigned target) {
    __syncthreads();
    if (threadIdx.x == 0) {
        __hip_atomic_store(&g_slots[blockIdx.x], target, __ATOMIC_RELEASE, __HIP_MEMORY_SCOPE_AGENT);
    }
    if (blockIdx.x == 0) {
        if (threadIdx.x < 64) {
            long guard = 0;
            for (;;) {
                bool ok = true;
                #pragma unroll
                for (int i = 0; i < 4; i++) {
                    unsigned v = __hip_atomic_load(&g_slots[threadIdx.x + i * 64],
                                                   __ATOMIC_RELAXED, __HIP_MEMORY_SCOPE_AGENT);
                    ok = ok && ((int)(v - target) >= 0);
                }
                if (__all(ok)) break;
                __builtin_amdgcn_s_sleep(2);
                if (++guard > (1L << 20)) break;
            }
            if (threadIdx.x == 0) {
                __hip_atomic_store(&g_gen2, target, __ATOMIC_RELEASE, __HIP_MEMORY_SCOPE_AGENT);
            }
        }
    } else if (threadIdx.x == 0) {
        long guard = 0;
        while ((int)(__hip_atomic_load(&g_gen2, __ATOMIC_RELAXED, __HIP_MEMORY_SCOPE_AGENT) - target) < 0) {
            __builtin_amdgcn_s_sleep(2);
            if (++guard > (1L << 20)) break;
        }
    }
    __syncthreads();
}

// LDS layout (floats): [0..12287] scratch (A: hS 4096 + partials 8192;
//   C: As 2048 + Bs 4096 + betaS 256; B: sL 64; D: 1024; E: 512; F: gp 1024)
// [12288..36863] WF (F-phase W_ih/W_hh rows, 8 x 768 float4)
// Total 36864 floats = 147,456 B (<160 KiB, 1 block/CU). G aliases [0..24575].
#define S_WF 12288

__global__ __launch_bounds__(NT, 4) void k_main(
    const float* __restrict__ enc, const int* __restrict__ caps, const int* __restrict__ caplen,
    const float* __restrict__ W_c, const float* __restrict__ b_c, const float* __restrict__ W_i_hat,
    const float* __restrict__ W_s, const float* __restrict__ b_s, const float* __restrict__ W_i,
    const float* __restrict__ emb,
    const float* __restrict__ W_ih, const float* __restrict__ W_hh,
    const float* __restrict__ b_ih, const float* __restrict__ b_hh,
    const float* __restrict__ W_init_h, const float* __restrict__ b_init_h,
    const float* __restrict__ W_init_c, const float* __restrict__ b_init_c,
    const float* __restrict__ W_hc, const float* __restrict__ W_hs,
    const float* __restrict__ W_fc, const float* __restrict__ b_fc,
    float* __restrict__ out, float* __restrict__ ws)
{
    __shared__ __align__(16) float smem[36864];

    float* vmean  = ws;                     // 16384  (single-write: cached reads OK)
    float* hbuf   = vmean + 16384;          // 4096   (multi-write: bypass reads)
    float* cbuf   = hbuf + 4096;            // 4096
    float* qpart  = cbuf + 4096;            // 2which*8b*512k = 8192 (final sums)
    float* beta   = qpart + 8192;           // 16384
    float* scoreS = beta + 16384;           // 512  [b][p]
    float* xcat   = scoreS + 512;           // 8*3072 = 24576
    float* hhist  = xcat + 24576;           // 96*512 = 49152
    float* spart  = hhist + 49152;          // 8ch*8b*64p*512k = 2097152 (8.4 MB)

    const int tid  = threadIdx.x;
    const int bid  = blockIdx.x;
    const int lane = tid & 63;
    const int bw   = tid >> 6;              // wave in block: 0..15
    const int gw   = bid * 16 + bw;         // global wave: 0..4095

    unsigned bt = __hip_atomic_load(&g_gen2, __ATOMIC_RELAXED, __HIP_MEMORY_SCOPE_AGENT);

    // ---- C-phase decomposition: XCD-aware (xcd = bid&7 under round-robin dispatch) ----
    const int xcdC   = bid & 7;
    const int innC   = bid >> 3;
    const int chunkC = ((innC & 3) << 1) | (xcdC & 1);               // 0..7 (256 c each)
    const int ktileC = (((innC >> 2) & 1) << 1) | ((xcdC >> 1) & 1); // 0..3 (128 k each)
    const int bC     = ((innC >> 3) << 1) | ((xcdC >> 2) & 1);       // 0..7

    // ================= one-time LDS weight staging (WF) =================
    {
        float4* wf4 = (float4*)(smem + S_WF);
        const float4* wih4 = (const float4*)W_ih;   // row = 640 f4
        const float4* whh4 = (const float4*)W_hh;   // row = 128 f4
        #pragma unroll
        for (int i = 0; i < 6; i++) {
            int f4i = i * 1024 + tid;               // 0..6143
            int r2  = f4i / 768;                    // 0..7 = g*2+dd
            int col = f4i - r2 * 768;
            int j   = (r2 >> 1) * 512 + bid * 2 + (r2 & 1);
            wf4[r2 * 768 + col] = (col < 640) ? wih4[(size_t)j * 640 + col]
                                              : whh4[(size_t)j * 128 + (col - 640)];
        }
    }

    // ================= phase 0: tail fills + Vmean =================
    {
        int gid = bid * NT + tid;
        const int base = Bz * Tz * Vz;
        const int nCap = Bz * T1z;
        const int nAlp = Bz * Tz * Pz;
        if (gid < nCap + Bz + nAlp + Bz) {
            if (gid < nCap) out[base + gid] = (float)caps[gid];
            else if (gid < nCap + Bz) out[base + gid] = (float)(caplen[gid - nCap] - 1);
            else if (gid < nCap + Bz + nAlp) out[base + gid] = 0.0f;
            else out[base + gid] = (float)(gid - (nCap + Bz + nAlp));
        }
        #pragma unroll
        for (int j = 0; j < 4; j++) {
            int w = gw * 4 + j;                     // 0..16383
            float v = enc[(size_t)w * 64 + lane];
            v = waveReduce(v);
            if (lane == 0) vmean[w] = v * (1.0f / 64.0f);
        }
    }
    gridSync(++bt);

    // ================= phase 1: h0 / c0 =================
    {
        #pragma unroll
        for (int j = 0; j < 2; j++) {
            int o = gw * 2 + j;                     // 0..8191
            int which = o >> 12;
            int rem = o & 4095;
            int b = rem >> 9, d = rem & 511;
            const float* W = which ? W_init_c : W_init_h;
            float acc = 0.0f;
            #pragma unroll 4
            for (int i = 0; i < 32; i++) {
                int cc = i * 64 + lane;
                acc = fmaf(vmean[b * Cz + cc], W[(size_t)d * Cz + cc], acc);
            }
            acc = waveReduce(acc);
            if (lane == 0) {
                if (which) cbuf[rem] = acc + b_init_c[d];
                else       hbuf[rem] = acc + b_init_h[d];
            }
        }
    }
    gridSync(++bt);

    for (int t = 0; t < Tz; t++) {
        // ========== A: FINAL q projections, 32 blocks (which, kslab of 32k) ==========
        {
            if (bid < 32) {
                const int whichA = bid & 1, kslabA = bid >> 1;
                const float* Wsel = whichA ? W_hs : W_hc;
                ((float4*)smem)[tid] = ldcv4a((const float4*)hbuf + tid);   // 1024 f4
                __syncthreads();
                int kk = tid & 31, dg = tid >> 5;   // dg 0..31 (16 d each)
                int k = kslabA * 32 + kk;
                float acc[8] = {0.f, 0.f, 0.f, 0.f, 0.f, 0.f, 0.f, 0.f};
                #pragma unroll 8
                for (int j = 0; j < 16; j++) {
                    int d = dg * 16 + j;
                    float wv = Wsel[(size_t)d * Kz + k];
                    #pragma unroll
                    for (int b = 0; b < 8; b++) acc[b] = fmaf(smem[b * 512 + d], wv, acc[b]);
                }
                #pragma unroll
                for (int b = 0; b < 8; b++) smem[4096 + dg * 256 + b * 32 + kk] = acc[b];
                __syncthreads();
                if (tid < 256) {
                    int b = tid >> 5, kk2 = tid & 31;
                    float s = 0.0f;
                    #pragma unroll
                    for (int dg2 = 0; dg2 < 32; dg2++) s += smem[4096 + dg2 * 256 + b * 32 + kk2];
                    qpart[(size_t)(whichA * 8 + b) * Kz + kslabA * 32 + kk2] = s;
                }
            }
            if (bid == 255 && tid < 512) scoreS[tid] = 0.0f;
        }
        gridSync(++bt);

        // ========== B: channel attention scores + batch softmax -> beta ==========
        // 16 waves: b = bw&7, ch2 = bw>>3 -> 4 c's per wave
        {
            float* sL = smem;               // [8 c][8 b]
            int b = bw & 7, ch2 = bw >> 3;
            const float4* wc4 = (const float4*)W_c;
            const float4* bc4 = (const float4*)b_c;
            const float4* wi4 = (const float4*)W_i_hat;
            int k0 = lane, k1 = 64 + lane;
            const float4* qb = (const float4*)qpart + b * 128 + k0;
            float4 qa, qe;
            ldcv4x2(qa, qe, qb, qb + 64);
            float4 q0 = bc4[k0], q1 = bc4[k1];
            q0.x += qa.x; q0.y += qa.y; q0.z += qa.z; q0.w += qa.w;
            q1.x += qe.x; q1.y += qe.y; q1.z += qe.z; q1.w += qe.w;
            float4 wcA = wc4[k0], wcB = wc4[k1];
            float4 wiA = wi4[k0], wiB = wi4[k1];
            #pragma unroll
            for (int j = 0; j < 4; j++) {
                int jj = ch2 * 4 + j;
                int cc = bid * 8 + jj;
                float v = vmean[b * Cz + cc];
                float acc = 0.0f;
                acc += tanhf(fmaf(v, wcA.x, q0.x)) * wiA.x;
                acc += tanhf(fmaf(v, wcA.y, q0.y)) * wiA.y;
                acc += tanhf(fmaf(v, wcA.z, q0.z)) * wiA.z;
                acc += tanhf(fmaf(v, wcA.w, q0.w)) * wiA.w;
                acc += tanhf(fmaf(v, wcB.x, q1.x)) * wiB.x;
                acc += tanhf(fmaf(v, wcB.y, q1.y)) * wiB.y;
                acc += tanhf(fmaf(v, wcB.z, q1.z)) * wiB.z;
                acc += tanhf(fmaf(v, wcB.w, q1.w)) * wiB.w;
                acc = waveReduce(acc);
                if (lane == 0) sL[jj * 8 + b] = acc;
            }
            __syncthreads();
            if (tid < 64) {
                int j = tid >> 3, b2 = tid & 7;
                float m = -1e30f;
                #pragma unroll
                for (int q = 0; q < 8; q++) m = fmaxf(m, sL[j * 8 + q]);
                float s = 0.0f;
                #pragma unroll
                for (int q = 0; q < 8; q++) s += expf(sL[j * 8 + q] - m);
                beta[b2 * Cz + bid * 8 + j] = expf(sL[j * 8 + b2] - m) / s;
            }
            __syncthreads();
        }
        gridSync(++bt);

        // ========== C: partial einsum spart[ch][b][p][k]; enc/W_s stay L2-warm ==========
        // 1024 threads: per-thread 2p x 4k; betaS staged once (kills 16x-redundant loads)
        {
            float* As = smem;               // [32][64]  (c x p, beta-scaled)
            float* Bs = smem + 2048;        // [32][128] (c x k)
            float* betaS = smem + 6144;     // 256
            if (tid < 256) betaS[tid] = ldcv(&beta[bC * Cz + chunkC * 256 + tid]);
            __syncthreads();
            int pq = tid >> 5;              // 32 groups x 2p
            int kq = tid & 31;              // 32 groups x 4k
            int k0 = ktileC * 128;
            float acc[2][4];
            #pragma unroll
            for (int i = 0; i < 2; i++)
                #pragma unroll
                for (int j = 0; j < 4; j++) acc[i][j] = 0.0f;

            for (int st = 0; st < 8; st++) {
                int c0 = chunkC * 256 + st * 32;
                if (tid < 512) {            // stage As: 512 f4
                    int cl = tid >> 4, p4 = tid & 15;
                    float btv = betaS[st * 32 + cl];
                    float4 ev = ((const float4*)enc)[(size_t)(bC * Cz + c0 + cl) * 16 + p4];
                    ((float4*)As)[cl * 16 + p4] = make_float4(ev.x * btv, ev.y * btv, ev.z * btv, ev.w * btv);
                }
                {                           // stage Bs: 1024 f4, 1/thread (W_s cached)
                    int cl = tid >> 5, kf = tid & 31;
                    ((float4*)Bs)[cl * 32 + kf] =
                        ((const float4*)W_s)[(size_t)(c0 + cl) * 128 + ktileC * 32 + kf];
                }
                __syncthreads();
                #pragma unroll 8
                for (int cc = 0; cc < 32; cc++) {
                    float a0 = As[cc * 64 + pq * 2];
                    float a1 = As[cc * 64 + pq * 2 + 1];
                    float4 bv = *(const float4*)&Bs[cc * 128 + kq * 4];
                    acc[0][0] = fmaf(a0, bv.x, acc[0][0]);
                    acc[0][1] = fmaf(a0, bv.y, acc[0][1]);
                    acc[0][2] = fmaf(a0, bv.z, acc[0][2]);
                    acc[0][3] = fmaf(a0, bv.w, acc[0][3]);
                    acc[1][0] = fmaf(a1, bv.x, acc[1][0]);
                    acc[1][1] = fmaf(a1, bv.y, acc[1][1]);
                    acc[1][2] = fmaf(a1, bv.z, acc[1][2]);
                    acc[1][3] = fmaf(a1, bv.w, acc[1][3]);
                }
                __syncthreads();
            }
            float* dst = spart + (size_t)((chunkC * Bz + bC) * Pz) * Kz + k0 + kq * 4;
            #pragma unroll
            for (int i = 0; i < 2; i++) {
                int p = pq * 2 + i;
                stcv4((float4*)&dst[(size_t)p * Kz],
                      make_float4(acc[i][0], acc[i][1], acc[i][2], acc[i][3]));
            }
        }
        gridSync(++bt);

        // ========== D: spatial scores (chunk halves split across waves) ==========
        // block = (p, k-quarter); wave: b = bw&7, sh2 = bw>>3; LDS combine of halves
        {
            int p = bid >> 2, kqr = bid & 3;
            int b = bw & 7, sh2 = bw >> 3;
            int kf = lane & 31;
            int sh = lane >> 5;
            int kg = kqr * 32 + kf;         // f4 index 0..127
            const float4* sp4 = (const float4*)spart;
            int ch0 = sh2 * 4 + sh * 2;
            size_t base = ((size_t)(ch0 * Bz + b) * 64 + p) * 128 + kg;
            const size_t chs = (size_t)Bz * 64 * 128;   // chunk stride in f4
            float4 t0, t1;
            ldcv4x2(t0, t1, sp4 + base, sp4 + base + chs);
            float sx = t0.x + t1.x, sy = t0.y + t1.y;
            float sz = t0.z + t1.z, sw = t0.w + t1.w;
            sx += __shfl_xor(sx, 32); sy += __shfl_xor(sy, 32);
            sz += __shfl_xor(sz, 32); sw += __shfl_xor(sw, 32);
            // waves sh2==1 publish their 4-chunk sums
            if (sh2 == 1 && sh == 0)
                ((float4*)smem)[b * 32 + kf] = make_float4(sx, sy, sz, sw);
            __syncthreads();
            if (sh2 == 0) {
                float acc = 0.0f;
                if (sh == 0) {
                    float4 o = ((float4*)smem)[b * 32 + kf];
                    sx += o.x; sy += o.y; sz += o.z; sw += o.w;
                    float4 q = ((const float4*)b_s)[kg];
                    float4 tq = ldcv4a(&((const float4*)qpart)[(8 + b) * 128 + kg]);
                    q.x += tq.x; q.y += tq.y; q.z += tq.z; q.w += tq.w;
                    float4 wi = ((const float4*)W_i)[kg];
                    acc = tanhf(sx + q.x) * wi.x + tanhf(sy + q.y) * wi.y +
                          tanhf(sz + q.z) * wi.z + tanhf(sw + q.w) * wi.w;
                }
                acc = waveReduce(acc);
                if (lane == 0) atomicAdd(&scoreS[b * 64 + p], acc);
            }
        }
        gridSync(++bt);

        // ========== E: alpha softmax (scoreS staged to LDS) + awe -> xcat ==========
        {
            if (tid < 128) {
                float4 s4 = ldcv4a(((const float4*)scoreS) + tid);
                ((float4*)smem)[tid] = s4;
            }
            __syncthreads();
            int b = gw >> 9;                // 0..7
            int cg = gw & 511;              // 0..511 (4 c each)
            float sc[8];
            #pragma unroll
            for (int bb = 0; bb < 8; bb++) sc[bb] = smem[bb * 64 + lane];
            float m = -1e30f;
            #pragma unroll
            for (int bb = 0; bb < 8; bb++) m = fmaxf(m, sc[bb]);
            float denom = 0.0f;
            #pragma unroll
            for (int bb = 0; bb < 8; bb++) denom += expf(sc[bb] - m);
            float aval = expf(sc[b] - m) / denom;   // alpha[b][p=lane]
            float bv = (lane < 4) ? ldcv(&beta[b * Cz + cg * 4 + lane]) : 0.0f;
            #pragma unroll
            for (int j = 0; j < 4; j++) {
                int cc = cg * 4 + j;
                float e = enc[(size_t)(b * Cz + cc) * 64 + lane];
                float v = waveReduce(e * aval);
                float bj = __shfl(bv, j);
                if (lane == 0) xcat[b * 3072 + Ez + cc] = bj * v * (1.0f / 64.0f);
            }
            int gid = bid * NT + tid;
            if (gid < 8192) {
                int b2 = gid >> 10, r = gid & 1023;
                if (r < Ez) xcat[b2 * 3072 + r] = emb[(size_t)caps[b2 * T1z + t] * Ez + r];
                else        xcat[b2 * 3072 + 2560 + (r - Ez)] = ldcv(&hbuf[b2 * Dz + (r - Ez)]);
            }
        }
        gridSync(++bt);

        // ========== F: gates (LDS weights) + LSTM cell; wave = e-sixteenth ==========
        {
            float* gp = smem;               // partials: [16 waves][8 rows][8 b] = 1024
            const float4* wf4 = (const float4*)(smem + S_WF);
            int b = lane >> 3, e8 = lane & 7;
            const float4* xb = (const float4*)xcat + b * 768 + bw * 48 + e8;
            float4 xv[6];
            asm volatile(
                "global_load_dwordx4 %0, %6, off sc0 sc1\n\t"
                "global_load_dwordx4 %1, %6, off offset:128 sc0 sc1\n\t"
                "global_load_dwordx4 %2, %6, off offset:256 sc0 sc1\n\t"
                "global_load_dwordx4 %3, %6, off offset:384 sc0 sc1\n\t"
                "global_load_dwordx4 %4, %6, off offset:512 sc0 sc1\n\t"
                "global_load_dwordx4 %5, %6, off offset:640 sc0 sc1\n\t"
                "s_waitcnt vmcnt(0)"
                : "=&v"(xv[0]), "=&v"(xv[1]), "=&v"(xv[2]),
                  "=&v"(xv[3]), "=&v"(xv[4]), "=&v"(xv[5])
                : "v"(xb) : "memory");
            float accg[8] = {0.f, 0.f, 0.f, 0.f, 0.f, 0.f, 0.f, 0.f};
            #pragma unroll
            for (int i = 0; i < 6; i++) {
                int ef4 = bw * 48 + i * 8 + e8;
                #pragma unroll
                for (int r2 = 0; r2 < 8; r2++) {
                    float4 w = wf4[r2 * 768 + ef4];
                    accg[r2] = fmaf(xv[i].x, w.x, accg[r2]);
                    accg[r2] = fmaf(xv[i].y, w.y, accg[r2]);
                    accg[r2] = fmaf(xv[i].z, w.z, accg[r2]);
                    accg[r2] = fmaf(xv[i].w, w.w, accg[r2]);
                }
            }
            #pragma unroll
            for (int mm = 1; mm < 8; mm <<= 1) {
                #pragma unroll
                for (int r2 = 0; r2 < 8; r2++) accg[r2] += __shfl_xor(accg[r2], mm);
            }
            if (e8 == 0) {
                #pragma unroll
                for (int r2 = 0; r2 < 8; r2++) gp[(bw * 8 + r2) * 8 + b] = accg[r2];
            }
            __syncthreads();
            if (tid < 16) {
                int b2 = tid & 7, ddd = tid >> 3;
                int d3 = bid * 2 + ddd;
                float gate[4];
                #pragma unroll
                for (int g = 0; g < 4; g++) {
                    float sum = 0.0f;
                    #pragma unroll
                    for (int qq = 0; qq < 16; qq++) sum += gp[(qq * 8 + g * 2 + ddd) * 8 + b2];
                    gate[g] = sum + b_ih[g * 512 + d3] + b_hh[g * 512 + d3];
                }
                int ci = b2 * 512 + d3;
                float cn = sigf(gate[1]) * ldcv(&cbuf[ci]) + sigf(gate[0]) * tanhf(gate[2]);
                cbuf[ci] = cn;
                float hn = sigf(gate[3]) * tanhf(cn);
                hbuf[ci] = hn;
                hhist[(t * 8 + b2) * 512 + d3] = hn;
            }
        }
        gridSync(++bt);
    }

    // ========== G: all predictions: out[96][20000] = h_hist @ W_fc^T ==========
    {
        int hr = bid & 1, vg = bid >> 1;
        if (vg < 125) {
            float4* hs4 = (float4*)smem;    // [48][128] f4 (aliases WF — t-loop done)
            const float4* hh4 = (const float4*)hhist + hr * 6144;
            #pragma unroll
            for (int i = 0; i < 6; i++) hs4[tid + i * 1024] = hh4[tid + i * 1024];
            __syncthreads();
            int r8 = lane >> 3, d8 = lane & 7;
            int vb = vg * 160 + bw * 10;
            float acc[10][6];
            #pragma unroll
            for (int vv = 0; vv < 10; vv++)
                #pragma unroll
                for (int rr = 0; rr < 6; rr++) acc[vv][rr] = 0.0f;
            for (int i = 0; i < 16; i++) {
                float4 h6[6];
                #pragma unroll
                for (int rr = 0; rr < 6; rr++) h6[rr] = hs4[(r8 * 6 + rr) * 128 + i * 8 + d8];
                #pragma unroll
                for (int vv = 0; vv < 10; vv++) {
                    float4 w = ((const float4*)W_fc)[(size_t)(vb + vv) * 128 + i * 8 + d8];
                    #pragma unroll
                    for (int rr = 0; rr < 6; rr++) {
                        acc[vv][rr] = fmaf(w.x, h6[rr].x, acc[vv][rr]);
                        acc[vv][rr] = fmaf(w.y, h6[rr].y, acc[vv][rr]);
                        acc[vv][rr] = fmaf(w.z, h6[rr].z, acc[vv][rr]);
                        acc[vv][rr] = fmaf(w.w, h6[rr].w, acc[vv][rr]);
                    }
                }
            }
            #pragma unroll
            for (int vv = 0; vv < 10; vv++) {
                #pragma unroll
                for (int rr = 0; rr < 6; rr++) {
                    float a = acc[vv][rr];
                    a += __shfl_xor(a, 1);
                    a += __shfl_xor(a, 2);
                    a += __shfl_xor(a, 4);
                    if (d8 == 0) {
                        int row = hr * 48 + r8 * 6 + rr;   // row = t*8 + b
                        int tt = row >> 3, b2 = row & 7;
                        out[((size_t)b2 * Tz + tt) * Vz + vb + vv] = a + b_fc[vb + vv];
                    }
                }
            }
        }
    }
}

extern "C" void kernel_launch(void* const* d_in, const int* in_sizes, int n_in,
                              void* d_out, int out_size, void* d_ws, size_t ws_size,
                              hipStream_t stream) {
    const float* enc      = (const float*)d_in[0];
    const int*   caps     = (const int*)d_in[1];
    const int*   caplen   = (const int*)d_in[2];
    const float* W_c      = (const float*)d_in[3];
    const float* W_hc     = (const float*)d_in[4];
    const float* W_i_hat  = (const float*)d_in[5];
    const float* b_c      = (const float*)d_in[6];
    const float* W_s      = (const float*)d_in[8];
    const float* W_hs     = (const float*)d_in[9];
    const float* W_i      = (const float*)d_in[10];
    const float* b_s      = (const float*)d_in[11];
    const float* emb      = (const float*)d_in[13];
    const float* W_ih     = (const float*)d_in[14];
    const float* W_hh     = (const float*)d_in[15];
    const float* b_ih     = (const float*)d_in[16];
    const float* b_hh     = (const float*)d_in[17];
    const float* W_init_h = (const float*)d_in[18];
    const float* b_init_h = (const float*)d_in[19];
    const float* W_init_c = (const float*)d_in[20];
    const float* b_init_c = (const float*)d_in[21];
    const float* W_fc     = (const float*)d_in[22];
    const float* b_fc     = (const float*)d_in[23];

    k_main<<<dim3(NB), dim3(NT), 0, stream>>>(
        enc, caps, caplen, W_c, b_c, W_i_hat, W_s, b_s, W_i, emb,
        W_ih, W_hh, b_ih, b_hh, W_init_h, b_init_h, W_init_c, b_init_c,
        W_hc, W_hs, W_fc, b_fc, (float*)d_out, (float*)d_ws);
}

// Round 8
// 1481.257 us; speedup vs baseline: 1.0092x; 1.0092x over previous
//
#include <hip/hip_runtime.h>

#define Bz 8
#define T1z 13
#define Tz 12
#define Vz 20000
#define Ez 512
#define Dz 512
#define Kz 512
#define Cz 2048
#define Pz 64
#define NB 256
#define NT 1024

typedef float floatx4 __attribute__((ext_vector_type(4)));

// ---- persistent-kernel grid barrier state (monotone generation counter) ----
__device__ unsigned g_slots[NB];
__device__ unsigned g_gen2;

__device__ __forceinline__ float waveReduce(float v) {
    #pragma unroll
    for (int off = 32; off > 0; off >>= 1) v += __shfl_xor(v, off);
    return v;
}

__device__ __forceinline__ float sigf(float x) { return 1.0f / (1.0f + expf(-x)); }

// Coherent (L1/L2-bypassing, NON-invalidating) scalar load.
__device__ __forceinline__ float ldcv(const float* p) {
    return __hip_atomic_load(p, __ATOMIC_RELAXED, __HIP_MEMORY_SCOPE_AGENT);
}

// Vector (dwordx4) coherent bypass loads; batched variants issue N loads
// before ONE waitcnt -> single L3 latency.
__device__ __forceinline__ float4 ldcv4a(const float4* p) {
    float4 r;
    asm volatile("global_load_dwordx4 %0, %1, off sc0 sc1\n\ts_waitcnt vmcnt(0)"
                 : "=&v"(r) : "v"(p) : "memory");
    return r;
}
__device__ __forceinline__ void ldcv4x2(float4& a, float4& b,
                                        const float4* pa, const float4* pb) {
    asm volatile("global_load_dwordx4 %0, %2, off sc0 sc1\n\t"
                 "global_load_dwordx4 %1, %3, off sc0 sc1\n\t"
                 "s_waitcnt vmcnt(0)"
                 : "=&v"(a), "=&v"(b) : "v"(pa), "v"(pb) : "memory");
}
// Coherent write-through store (value must be ext_vector_type, not float4 struct:
// clang can't pass struct INPUTS in a 'v' constraint; struct outputs are fine).
__device__ __forceinline__ void stcv4(float4* p, float4 v) {
    floatx4 w;
    w.x = v.x; w.y = v.y; w.z = v.z; w.w = v.w;
    asm volatile("global_store_dwordx4 %0, %1, off sc0 sc1" :: "v"(p), "v"(w) : "memory");
}

// Grid-wide barrier: RELAXED polls; ONE release store at arrival. No invalidate:
// cross-phase intermediates are read via bypass loads, L2 read-caches survive.
__device__ __forceinline__ void gridSync(unsigned target) {
    __syncthreads();
    if (threadIdx.x == 0) {
        __hip_atomic_store(&g_slots[blockIdx.x], target, __ATOMIC_RELEASE, __HIP_MEMORY_SCOPE_AGENT);
    }
    if (blockIdx.x == 0) {
        if (threadIdx.x < 64) {
            long guard = 0;
            for (;;) {
                bool ok = true;
                #pragma unroll
                for (int i = 0; i < 4; i++) {
                    unsigned v = __hip_atomic_load(&g_slots[threadIdx.x + i * 64],
                                                   __ATOMIC_RELAXED, __HIP_MEMORY_SCOPE_AGENT);
                    ok = ok && ((int)(v - target) >= 0);
                }
                if (__all(ok)) break;
                __builtin_amdgcn_s_sleep(2);
                if (++guard > (1L << 20)) break;
            }
            if (threadIdx.x == 0) {
                __hip_atomic_store(&g_gen2, target, __ATOMIC_RELEASE, __HIP_MEMORY_SCOPE_AGENT);
            }
        }
    } else if (threadIdx.x == 0) {
        long guard = 0;
        while ((int)(__hip_atomic_load(&g_gen2, __ATOMIC_RELAXED, __HIP_MEMORY_SCOPE_AGENT) - target) < 0) {
            __builtin_amdgcn_s_sleep(2);
            if (++guard > (1L << 20)) break;
        }
    }
    __syncthreads();
}

// LDS layout (floats): [0..12287] scratch (A: hS 4096 + partials 8192;
//   C: As 2048 + Bs 4096 + betaS 256; B: sL 64; D: 1024; E: 512; F: gp 1024)
// [12288..36863] WF (F-phase W_ih/W_hh rows, 8 x 768 float4)
// Total 36864 floats = 147,456 B (<160 KiB, 1 block/CU). G aliases [0..24575].
#define S_WF 12288

// __launch_bounds__ 2nd arg: measured toolchain behavior is CUDA-style
// min-BLOCKS-per-CU (r6: (512,2)->128 VGPR = 16-wave cap; r7: (1024,4)->64 VGPR
// = 32-wave cap + 1GB scratch spill in G). Declare 1 resident block -> VGPR
// cap 128 (launchability of a 1024-thread block), no spills, 16 waves/CU.
__global__ __launch_bounds__(NT, 1) void k_main(
    const float* __restrict__ enc, const int* __restrict__ caps, const int* __restrict__ caplen,
    const float* __restrict__ W_c, const float* __restrict__ b_c, const float* __restrict__ W_i_hat,
    const float* __restrict__ W_s, const float* __restrict__ b_s, const float* __restrict__ W_i,
    const float* __restrict__ emb,
    const float* __restrict__ W_ih, const float* __restrict__ W_hh,
    const float* __restrict__ b_ih, const float* __restrict__ b_hh,
    const float* __restrict__ W_init_h, const float* __restrict__ b_init_h,
    const float* __restrict__ W_init_c, const float* __restrict__ b_init_c,
    const float* __restrict__ W_hc, const float* __restrict__ W_hs,
    const float* __restrict__ W_fc, const float* __restrict__ b_fc,
    float* __restrict__ out, float* __restrict__ ws)
{
    __shared__ __align__(16) float smem[36864];

    float* vmean  = ws;                     // 16384  (single-write: cached reads OK)
    float* hbuf   = vmean + 16384;          // 4096   (multi-write: bypass reads)
    float* cbuf   = hbuf + 4096;            // 4096
    float* qpart  = cbuf + 4096;            // 2which*8b*512k = 8192 (final sums)
    float* beta   = qpart + 8192;           // 16384
    float* scoreS = beta + 16384;           // 512  [b][p]
    float* xcat   = scoreS + 512;           // 8*3072 = 24576
    float* hhist  = xcat + 24576;           // 96*512 = 49152
    float* spart  = hhist + 49152;          // 8ch*8b*64p*512k = 2097152 (8.4 MB)

    const int tid  = threadIdx.x;
    const int bid  = blockIdx.x;
    const int lane = tid & 63;
    const int bw   = tid >> 6;              // wave in block: 0..15
    const int gw   = bid * 16 + bw;         // global wave: 0..4095

    unsigned bt = __hip_atomic_load(&g_gen2, __ATOMIC_RELAXED, __HIP_MEMORY_SCOPE_AGENT);

    // ---- C-phase decomposition: XCD-aware (xcd = bid&7 under round-robin dispatch) ----
    const int xcdC   = bid & 7;
    const int innC   = bid >> 3;
    const int chunkC = ((innC & 3) << 1) | (xcdC & 1);               // 0..7 (256 c each)
    const int ktileC = (((innC >> 2) & 1) << 1) | ((xcdC >> 1) & 1); // 0..3 (128 k each)
    const int bC     = ((innC >> 3) << 1) | ((xcdC >> 2) & 1);       // 0..7

    // ================= one-time LDS weight staging (WF) =================
    {
        float4* wf4 = (float4*)(smem + S_WF);
        const float4* wih4 = (const float4*)W_ih;   // row = 640 f4
        const float4* whh4 = (const float4*)W_hh;   // row = 128 f4
        #pragma unroll
        for (int i = 0; i < 6; i++) {
            int f4i = i * 1024 + tid;               // 0..6143
            int r2  = f4i / 768;                    // 0..7 = g*2+dd
            int col = f4i - r2 * 768;
            int j   = (r2 >> 1) * 512 + bid * 2 + (r2 & 1);
            wf4[r2 * 768 + col] = (col < 640) ? wih4[(size_t)j * 640 + col]
                                              : whh4[(size_t)j * 128 + (col - 640)];
        }
    }

    // ================= phase 0: tail fills + Vmean =================
    {
        int gid = bid * NT + tid;
        const int base = Bz * Tz * Vz;
        const int nCap = Bz * T1z;
        const int nAlp = Bz * Tz * Pz;
        if (gid < nCap + Bz + nAlp + Bz) {
            if (gid < nCap) out[base + gid] = (float)caps[gid];
            else if (gid < nCap + Bz) out[base + gid] = (float)(caplen[gid - nCap] - 1);
            else if (gid < nCap + Bz + nAlp) out[base + gid] = 0.0f;
            else out[base + gid] = (float)(gid - (nCap + Bz + nAlp));
        }
        #pragma unroll
        for (int j = 0; j < 4; j++) {
            int w = gw * 4 + j;                     // 0..16383
            float v = enc[(size_t)w * 64 + lane];
            v = waveReduce(v);
            if (lane == 0) vmean[w] = v * (1.0f / 64.0f);
        }
    }
    gridSync(++bt);

    // ================= phase 1: h0 / c0 =================
    {
        #pragma unroll
        for (int j = 0; j < 2; j++) {
            int o = gw * 2 + j;                     // 0..8191
            int which = o >> 12;
            int rem = o & 4095;
            int b = rem >> 9, d = rem & 511;
            const float* W = which ? W_init_c : W_init_h;
            float acc = 0.0f;
            #pragma unroll 4
            for (int i = 0; i < 32; i++) {
                int cc = i * 64 + lane;
                acc = fmaf(vmean[b * Cz + cc], W[(size_t)d * Cz + cc], acc);
            }
            acc = waveReduce(acc);
            if (lane == 0) {
                if (which) cbuf[rem] = acc + b_init_c[d];
                else       hbuf[rem] = acc + b_init_h[d];
            }
        }
    }
    gridSync(++bt);

    for (int t = 0; t < Tz; t++) {
        // ========== A: FINAL q projections, 32 blocks (which, kslab of 32k) ==========
        {
            if (bid < 32) {
                const int whichA = bid & 1, kslabA = bid >> 1;
                const float* Wsel = whichA ? W_hs : W_hc;
                ((float4*)smem)[tid] = ldcv4a((const float4*)hbuf + tid);   // 1024 f4
                __syncthreads();
                int kk = tid & 31, dg = tid >> 5;   // dg 0..31 (16 d each)
                int k = kslabA * 32 + kk;
                float acc[8] = {0.f, 0.f, 0.f, 0.f, 0.f, 0.f, 0.f, 0.f};
                #pragma unroll 8
                for (int j = 0; j < 16; j++) {
                    int d = dg * 16 + j;
                    float wv = Wsel[(size_t)d * Kz + k];
                    #pragma unroll
                    for (int b = 0; b < 8; b++) acc[b] = fmaf(smem[b * 512 + d], wv, acc[b]);
                }
                #pragma unroll
                for (int b = 0; b < 8; b++) smem[4096 + dg * 256 + b * 32 + kk] = acc[b];
                __syncthreads();
                if (tid < 256) {
                    int b = tid >> 5, kk2 = tid & 31;
                    float s = 0.0f;
                    #pragma unroll
                    for (int dg2 = 0; dg2 < 32; dg2++) s += smem[4096 + dg2 * 256 + b * 32 + kk2];
                    qpart[(size_t)(whichA * 8 + b) * Kz + kslabA * 32 + kk2] = s;
                }
            }
            if (bid == 255 && tid < 512) scoreS[tid] = 0.0f;
        }
        gridSync(++bt);

        // ========== B: channel attention scores + batch softmax -> beta ==========
        // 16 waves: b = bw&7, ch2 = bw>>3 -> 4 c's per wave
        {
            float* sL = smem;               // [8 c][8 b]
            int b = bw & 7, ch2 = bw >> 3;
            const float4* wc4 = (const float4*)W_c;
            const float4* bc4 = (const float4*)b_c;
            const float4* wi4 = (const float4*)W_i_hat;
            int k0 = lane, k1 = 64 + lane;
            const float4* qb = (const float4*)qpart + b * 128 + k0;
            float4 qa, qe;
            ldcv4x2(qa, qe, qb, qb + 64);
            float4 q0 = bc4[k0], q1 = bc4[k1];
            q0.x += qa.x; q0.y += qa.y; q0.z += qa.z; q0.w += qa.w;
            q1.x += qe.x; q1.y += qe.y; q1.z += qe.z; q1.w += qe.w;
            float4 wcA = wc4[k0], wcB = wc4[k1];
            float4 wiA = wi4[k0], wiB = wi4[k1];
            #pragma unroll
            for (int j = 0; j < 4; j++) {
                int jj = ch2 * 4 + j;
                int cc = bid * 8 + jj;
                float v = vmean[b * Cz + cc];
                float acc = 0.0f;
                acc += tanhf(fmaf(v, wcA.x, q0.x)) * wiA.x;
                acc += tanhf(fmaf(v, wcA.y, q0.y)) * wiA.y;
                acc += tanhf(fmaf(v, wcA.z, q0.z)) * wiA.z;
                acc += tanhf(fmaf(v, wcA.w, q0.w)) * wiA.w;
                acc += tanhf(fmaf(v, wcB.x, q1.x)) * wiB.x;
                acc += tanhf(fmaf(v, wcB.y, q1.y)) * wiB.y;
                acc += tanhf(fmaf(v, wcB.z, q1.z)) * wiB.z;
                acc += tanhf(fmaf(v, wcB.w, q1.w)) * wiB.w;
                acc = waveReduce(acc);
                if (lane == 0) sL[jj * 8 + b] = acc;
            }
            __syncthreads();
            if (tid < 64) {
                int j = tid >> 3, b2 = tid & 7;
                float m = -1e30f;
                #pragma unroll
                for (int q = 0; q < 8; q++) m = fmaxf(m, sL[j * 8 + q]);
                float s = 0.0f;
                #pragma unroll
                for (int q = 0; q < 8; q++) s += expf(sL[j * 8 + q] - m);
                beta[b2 * Cz + bid * 8 + j] = expf(sL[j * 8 + b2] - m) / s;
            }
            __syncthreads();
        }
        gridSync(++bt);

        // ========== C: partial einsum spart[ch][b][p][k]; enc/W_s stay L2-warm ==========
        // 1024 threads: per-thread 2p x 4k; betaS staged once (kills 16x-redundant loads)
        {
            float* As = smem;               // [32][64]  (c x p, beta-scaled)
            float* Bs = smem + 2048;        // [32][128] (c x k)
            float* betaS = smem + 6144;     // 256
            if (tid < 256) betaS[tid] = ldcv(&beta[bC * Cz + chunkC * 256 + tid]);
            __syncthreads();
            int pq = tid >> 5;              // 32 groups x 2p
            int kq = tid & 31;              // 32 groups x 4k
            int k0 = ktileC * 128;
            float acc[2][4];
            #pragma unroll
            for (int i = 0; i < 2; i++)
                #pragma unroll
                for (int j = 0; j < 4; j++) acc[i][j] = 0.0f;

            for (int st = 0; st < 8; st++) {
                int c0 = chunkC * 256 + st * 32;
                if (tid < 512) {            // stage As: 512 f4
                    int cl = tid >> 4, p4 = tid & 15;
                    float btv = betaS[st * 32 + cl];
                    float4 ev = ((const float4*)enc)[(size_t)(bC * Cz + c0 + cl) * 16 + p4];
                    ((float4*)As)[cl * 16 + p4] = make_float4(ev.x * btv, ev.y * btv, ev.z * btv, ev.w * btv);
                }
                {                           // stage Bs: 1024 f4, 1/thread (W_s cached)
                    int cl = tid >> 5, kf = tid & 31;
                    ((float4*)Bs)[cl * 32 + kf] =
                        ((const float4*)W_s)[(size_t)(c0 + cl) * 128 + ktileC * 32 + kf];
                }
                __syncthreads();
                #pragma unroll 8
                for (int cc = 0; cc < 32; cc++) {
                    float a0 = As[cc * 64 + pq * 2];
                    float a1 = As[cc * 64 + pq * 2 + 1];
                    float4 bv = *(const float4*)&Bs[cc * 128 + kq * 4];
                    acc[0][0] = fmaf(a0, bv.x, acc[0][0]);
                    acc[0][1] = fmaf(a0, bv.y, acc[0][1]);
                    acc[0][2] = fmaf(a0, bv.z, acc[0][2]);
                    acc[0][3] = fmaf(a0, bv.w, acc[0][3]);
                    acc[1][0] = fmaf(a1, bv.x, acc[1][0]);
                    acc[1][1] = fmaf(a1, bv.y, acc[1][1]);
                    acc[1][2] = fmaf(a1, bv.z, acc[1][2]);
                    acc[1][3] = fmaf(a1, bv.w, acc[1][3]);
                }
                __syncthreads();
            }
            float* dst = spart + (size_t)((chunkC * Bz + bC) * Pz) * Kz + k0 + kq * 4;
            #pragma unroll
            for (int i = 0; i < 2; i++) {
                int p = pq * 2 + i;
                stcv4((float4*)&dst[(size_t)p * Kz],
                      make_float4(acc[i][0], acc[i][1], acc[i][2], acc[i][3]));
            }
        }
        gridSync(++bt);

        // ========== D: spatial scores (chunk halves split across waves) ==========
        // block = (p, k-quarter); wave: b = bw&7, sh2 = bw>>3; LDS combine of halves
        {
            int p = bid >> 2, kqr = bid & 3;
            int b = bw & 7, sh2 = bw >> 3;
            int kf = lane & 31;
            int sh = lane >> 5;
            int kg = kqr * 32 + kf;         // f4 index 0..127
            const float4* sp4 = (const float4*)spart;
            int ch0 = sh2 * 4 + sh * 2;
            size_t base = ((size_t)(ch0 * Bz + b) * 64 + p) * 128 + kg;
            const size_t chs = (size_t)Bz * 64 * 128;   // chunk stride in f4
            float4 t0, t1;
            ldcv4x2(t0, t1, sp4 + base, sp4 + base + chs);
            float sx = t0.x + t1.x, sy = t0.y + t1.y;
            float sz = t0.z + t1.z, sw = t0.w + t1.w;
            sx += __shfl_xor(sx, 32); sy += __shfl_xor(sy, 32);
            sz += __shfl_xor(sz, 32); sw += __shfl_xor(sw, 32);
            // waves sh2==1 publish their 4-chunk sums
            if (sh2 == 1 && sh == 0)
                ((float4*)smem)[b * 32 + kf] = make_float4(sx, sy, sz, sw);
            __syncthreads();
            if (sh2 == 0) {
                float acc = 0.0f;
                if (sh == 0) {
                    float4 o = ((float4*)smem)[b * 32 + kf];
                    sx += o.x; sy += o.y; sz += o.z; sw += o.w;
                    float4 q = ((const float4*)b_s)[kg];
                    float4 tq = ldcv4a(&((const float4*)qpart)[(8 + b) * 128 + kg]);
                    q.x += tq.x; q.y += tq.y; q.z += tq.z; q.w += tq.w;
                    float4 wi = ((const float4*)W_i)[kg];
                    acc = tanhf(sx + q.x) * wi.x + tanhf(sy + q.y) * wi.y +
                          tanhf(sz + q.z) * wi.z + tanhf(sw + q.w) * wi.w;
                }
                acc = waveReduce(acc);
                if (lane == 0) atomicAdd(&scoreS[b * 64 + p], acc);
            }
        }
        gridSync(++bt);

        // ========== E: alpha softmax (scoreS staged to LDS) + awe -> xcat ==========
        {
            if (tid < 128) {
                float4 s4 = ldcv4a(((const float4*)scoreS) + tid);
                ((float4*)smem)[tid] = s4;
            }
            __syncthreads();
            int b = gw >> 9;                // 0..7
            int cg = gw & 511;              // 0..511 (4 c each)
            float sc[8];
            #pragma unroll
            for (int bb = 0; bb < 8; bb++) sc[bb] = smem[bb * 64 + lane];
            float m = -1e30f;
            #pragma unroll
            for (int bb = 0; bb < 8; bb++) m = fmaxf(m, sc[bb]);
            float denom = 0.0f;
            #pragma unroll
            for (int bb = 0; bb < 8; bb++) denom += expf(sc[bb] - m);
            float aval = expf(sc[b] - m) / denom;   // alpha[b][p=lane]
            float bv = (lane < 4) ? ldcv(&beta[b * Cz + cg * 4 + lane]) : 0.0f;
            #pragma unroll
            for (int j = 0; j < 4; j++) {
                int cc = cg * 4 + j;
                float e = enc[(size_t)(b * Cz + cc) * 64 + lane];
                float v = waveReduce(e * aval);
                float bj = __shfl(bv, j);
                if (lane == 0) xcat[b * 3072 + Ez + cc] = bj * v * (1.0f / 64.0f);
            }
            int gid = bid * NT + tid;
            if (gid < 8192) {
                int b2 = gid >> 10, r = gid & 1023;
                if (r < Ez) xcat[b2 * 3072 + r] = emb[(size_t)caps[b2 * T1z + t] * Ez + r];
                else        xcat[b2 * 3072 + 2560 + (r - Ez)] = ldcv(&hbuf[b2 * Dz + (r - Ez)]);
            }
        }
        gridSync(++bt);

        // ========== F: gates (LDS weights) + LSTM cell; wave = e-sixteenth ==========
        {
            float* gp = smem;               // partials: [16 waves][8 rows][8 b] = 1024
            const float4* wf4 = (const float4*)(smem + S_WF);
            int b = lane >> 3, e8 = lane & 7;
            const float4* xb = (const float4*)xcat + b * 768 + bw * 48 + e8;
            float4 xv[6];
            asm volatile(
                "global_load_dwordx4 %0, %6, off sc0 sc1\n\t"
                "global_load_dwordx4 %1, %6, off offset:128 sc0 sc1\n\t"
                "global_load_dwordx4 %2, %6, off offset:256 sc0 sc1\n\t"
                "global_load_dwordx4 %3, %6, off offset:384 sc0 sc1\n\t"
                "global_load_dwordx4 %4, %6, off offset:512 sc0 sc1\n\t"
                "global_load_dwordx4 %5, %6, off offset:640 sc0 sc1\n\t"
                "s_waitcnt vmcnt(0)"
                : "=&v"(xv[0]), "=&v"(xv[1]), "=&v"(xv[2]),
                  "=&v"(xv[3]), "=&v"(xv[4]), "=&v"(xv[5])
                : "v"(xb) : "memory");
            float accg[8] = {0.f, 0.f, 0.f, 0.f, 0.f, 0.f, 0.f, 0.f};
            #pragma unroll
            for (int i = 0; i < 6; i++) {
                int ef4 = bw * 48 + i * 8 + e8;
                #pragma unroll
                for (int r2 = 0; r2 < 8; r2++) {
                    float4 w = wf4[r2 * 768 + ef4];
                    accg[r2] = fmaf(xv[i].x, w.x, accg[r2]);
                    accg[r2] = fmaf(xv[i].y, w.y, accg[r2]);
                    accg[r2] = fmaf(xv[i].z, w.z, accg[r2]);
                    accg[r2] = fmaf(xv[i].w, w.w, accg[r2]);
                }
            }
            #pragma unroll
            for (int mm = 1; mm < 8; mm <<= 1) {
                #pragma unroll
                for (int r2 = 0; r2 < 8; r2++) accg[r2] += __shfl_xor(accg[r2], mm);
            }
            if (e8 == 0) {
                #pragma unroll
                for (int r2 = 0; r2 < 8; r2++) gp[(bw * 8 + r2) * 8 + b] = accg[r2];
            }
            __syncthreads();
            if (tid < 16) {
                int b2 = tid & 7, ddd = tid >> 3;
                int d3 = bid * 2 + ddd;
                float gate[4];
                #pragma unroll
                for (int g = 0; g < 4; g++) {
                    float sum = 0.0f;
                    #pragma unroll
                    for (int qq = 0; qq < 16; qq++) sum += gp[(qq * 8 + g * 2 + ddd) * 8 + b2];
                    gate[g] = sum + b_ih[g * 512 + d3] + b_hh[g * 512 + d3];
                }
                int ci = b2 * 512 + d3;
                float cn = sigf(gate[1]) * ldcv(&cbuf[ci]) + sigf(gate[0]) * tanhf(gate[2]);
                cbuf[ci] = cn;
                float hn = sigf(gate[3]) * tanhf(cn);
                hbuf[ci] = hn;
                hhist[(t * 8 + b2) * 512 + d3] = hn;
            }
        }
        gridSync(++bt);
    }

    // ========== G: all predictions: out[96][20000] = h_hist @ W_fc^T ==========
    {
        int hr = bid & 1, vg = bid >> 1;
        if (vg < 125) {
            float4* hs4 = (float4*)smem;    // [48][128] f4 (aliases WF — t-loop done)
            const float4* hh4 = (const float4*)hhist + hr * 6144;
            #pragma unroll
            for (int i = 0; i < 6; i++) hs4[tid + i * 1024] = hh4[tid + i * 1024];
            __syncthreads();
            int r8 = lane >> 3, d8 = lane & 7;
            int vb = vg * 160 + bw * 10;
            float acc[10][6];
            #pragma unroll
            for (int vv = 0; vv < 10; vv++)
                #pragma unroll
                for (int rr = 0; rr < 6; rr++) acc[vv][rr] = 0.0f;
            for (int i = 0; i < 16; i++) {
                float4 h6[6];
                #pragma unroll
                for (int rr = 0; rr < 6; rr++) h6[rr] = hs4[(r8 * 6 + rr) * 128 + i * 8 + d8];
                #pragma unroll
                for (int vv = 0; vv < 10; vv++) {
                    float4 w = ((const float4*)W_fc)[(size_t)(vb + vv) * 128 + i * 8 + d8];
                    #pragma unroll
                    for (int rr = 0; rr < 6; rr++) {
                        acc[vv][rr] = fmaf(w.x, h6[rr].x, acc[vv][rr]);
                        acc[vv][rr] = fmaf(w.y, h6[rr].y, acc[vv][rr]);
                        acc[vv][rr] = fmaf(w.z, h6[rr].z, acc[vv][rr]);
                        acc[vv][rr] = fmaf(w.w, h6[rr].w, acc[vv][rr]);
                    }
                }
            }
            #pragma unroll
            for (int vv = 0; vv < 10; vv++) {
                #pragma unroll
                for (int rr = 0; rr < 6; rr++) {
                    float a = acc[vv][rr];
                    a += __shfl_xor(a, 1);
                    a += __shfl_xor(a, 2);
                    a += __shfl_xor(a, 4);
                    if (d8 == 0) {
                        int row = hr * 48 + r8 * 6 + rr;   // row = t*8 + b
                        int tt = row >> 3, b2 = row & 7;
                        out[((size_t)b2 * Tz + tt) * Vz + vb + vv] = a + b_fc[vb + vv];
                    }
                }
            }
        }
    }
}

extern "C" void kernel_launch(void* const* d_in, const int* in_sizes, int n_in,
                              void* d_out, int out_size, void* d_ws, size_t ws_size,
                              hipStream_t stream) {
    const float* enc      = (const float*)d_in[0];
    const int*   caps     = (const int*)d_in[1];
    const int*   caplen   = (const int*)d_in[2];
    const float* W_c      = (const float*)d_in[3];
    const float* W_hc     = (const float*)d_in[4];
    const float* W_i_hat  = (const float*)d_in[5];
    const float* b_c      = (const float*)d_in[6];
    const float* W_s      = (const float*)d_in[8];
    const float* W_hs     = (const float*)d_in[9];
    const float* W_i      = (const float*)d_in[10];
    const float* b_s      = (const float*)d_in[11];
    const float* emb      = (const float*)d_in[13];
    const float* W_ih     = (const float*)d_in[14];
    const float* W_hh     = (const float*)d_in[15];
    const float* b_ih     = (const float*)d_in[16];
    const float* b_hh     = (const float*)d_in[17];
    const float* W_init_h = (const float*)d_in[18];
    const float* b_init_h = (const float*)d_in[19];
    const float* W_init_c = (const float*)d_in[20];
    const float* b_init_c = (const float*)d_in[21];
    const float* W_fc     = (const float*)d_in[22];
    const float* b_fc     = (const float*)d_in[23];

    k_main<<<dim3(NB), dim3(NT), 0, stream>>>(
        enc, caps, caplen, W_c, b_c, W_i_hat, W_s, b_s, W_i, emb,
        W_ih, W_hh, b_ih, b_hh, W_init_h, b_init_h, W_init_c, b_init_c,
        W_hc, W_hs, W_fc, b_fc, (float*)d_out, (float*)d_ws);
}